// Round 10
// baseline (301.344 us; speedup 1.0000x reference)
//
#include <hip/hip_runtime.h>
#include <hip/hip_bf16.h>
#include <cstdint>
#include <cstddef>

#define B_DIM 4096
#define IN_F 4096
#define OUT_F 4096
#define NNZ_N 1677722

typedef short short8 __attribute__((ext_vector_type(8)));
typedef float floatx4 __attribute__((ext_vector_type(4)));
typedef unsigned short ushort8 __attribute__((ext_vector_type(8)));

// ---------------------------------------------------------------------------
// f32 -> bf16 RNE
// ---------------------------------------------------------------------------
__device__ inline unsigned short f2bf(float f) {
  union { float f; unsigned int u; } v;
  v.f = f;
  unsigned int u = v.u;
  return (unsigned short)((u + 0x7fffu + ((u >> 16) & 1u)) >> 16);
}

// ---------------------------------------------------------------------------
// R10: cvt split into its own ZERO-LDS kernel. In R9 it rode inside p1 and
// inherited the kernel's static 136KB LDS -> 1 block/CU, single-shot blocks,
// ~8 serial block-rounds with no pipelining — the only preprocessing term
// never isolated and the biggest data mover (96 MB). Canonical BW shape:
// 2048 blocks x 256 threads (8 blocks/CU), grid-stride x4, coalesced
// float4x2 -> ushort8.
// ---------------------------------------------------------------------------
#define CVT_BLOCKS 2048
#define CVT_THREADS 256
#define CVT_TOTAL_THREADS (CVT_BLOCKS * CVT_THREADS)  // 524288
#define CVT_VECS ((B_DIM * IN_F) / 8)                 // 2097152

__global__ __launch_bounds__(CVT_THREADS) void cvt_x(
    const float* __restrict__ x, unsigned short* __restrict__ xb) {
  unsigned int g = blockIdx.x * CVT_THREADS + threadIdx.x;
#pragma unroll
  for (int k = 0; k < 4; ++k) {
    size_t i = ((size_t)(g + k * CVT_TOTAL_THREADS)) * 8;
    float4 a = *(const float4*)(x + i);
    float4 f = *(const float4*)(x + i + 4);
    ushort8 o;
    o[0] = f2bf(a.x); o[1] = f2bf(a.y); o[2] = f2bf(a.z); o[3] = f2bf(a.w);
    o[4] = f2bf(f.x); o[5] = f2bf(f.y); o[6] = f2bf(f.z); o[7] = f2bf(f.w);
    *(ushort8*)(xb + i) = o;
  }
}

// ---------------------------------------------------------------------------
// Bucketed densification, fixed-slot layout (R9, proven): zero global
// atomics, 2-barrier scan. 103 blocks x 16384 elems; per (block,bucket)
// cell owns a fixed 76-slot run in seg. Cell count ~ Poisson(32);
// P(any cell > 76) ~= 2e-5, deterministic for this fixed input.
// ---------------------------------------------------------------------------
#define P1_CHUNK 16384
#define P1_BLOCKS 103  // ceil(NNZ / 16384)
#define NBUCK 512      // 8 rows per bucket
#define SLOT 76        // fixed slots per (block,bucket); seg = 30.6 MiB

__global__ __launch_bounds__(1024) void p1_bucket(
    const float* __restrict__ vals, const int* __restrict__ rows,
    const int* __restrict__ cols, unsigned int* __restrict__ cnt_arr,
    unsigned long long* __restrict__ seg) {
  __shared__ unsigned int cnt[NBUCK];   // per-bucket count
  __shared__ unsigned int off[NBUCK];   // inclusive scan
  __shared__ unsigned int offx[NBUCK];  // exclusive offsets
  __shared__ unsigned int cur2[NBUCK];  // placement cursors
  __shared__ unsigned long long stage[P1_CHUNK];  // 128 KB bucket-ordered
  const int b = blockIdx.x;
  const int tid = threadIdx.x;
  if (tid < NBUCK) cnt[tid] = 0;
  __syncthreads();
  const int base = b * P1_CHUNK;
  // ---- pass A: histogram ----
#pragma unroll
  for (int j = 0; j < P1_CHUNK / 1024; ++j) {
    int idx = base + j * 1024 + tid;
    if (idx < NNZ_N) atomicAdd(&cnt[rows[idx] >> 3], 1u);
  }
  __syncthreads();
  // ---- scan: wave 0 scans all 512 buckets (serial-8 + shfl_up) ----
  if (tid < 64) {
    unsigned int a[8];
#pragma unroll
    for (int i = 0; i < 8; ++i) a[i] = cnt[tid * 8 + i];
#pragma unroll
    for (int i = 1; i < 8; ++i) a[i] += a[i - 1];
    unsigned int ls = a[7];
    unsigned int sc = ls;
#pragma unroll
    for (int d = 1; d < 64; d <<= 1) {
      unsigned int o = __shfl_up(sc, d, 64);
      if (tid >= d) sc += o;
    }
    unsigned int excl = sc - ls;
#pragma unroll
    for (int i = 0; i < 8; ++i) off[tid * 8 + i] = a[i] + excl;
  }
  __syncthreads();
  if (tid < NBUCK) {
    unsigned int e = off[tid] - cnt[tid];
    offx[tid] = e;
    cur2[tid] = e;
    cnt_arr[(size_t)tid * P1_BLOCKS + b] = cnt[tid];  // plain store
  }
  __syncthreads();
  // ---- pass B: ranked placement into LDS stage (bucket-ordered) ----
#pragma unroll
  for (int j = 0; j < P1_CHUNK / 1024; ++j) {
    int idx = base + j * 1024 + tid;
    if (idx < NNZ_N) {
      int r = rows[idx];
      int c = cols[idx];
      union { float f; unsigned int u; } v;
      v.f = vals[idx];
      unsigned int slot = atomicAdd(&cur2[r >> 3], 1u);
      unsigned int key = (((unsigned int)r) << 12) | (unsigned int)c;
      stage[slot] = ((unsigned long long)v.u << 32) | key;
    }
  }
  __syncthreads();
  // ---- pass C: coalesced copy-out to fixed-slot runs ----
  unsigned int tot = off[NBUCK - 1];
  for (unsigned int k = tid; k < tot; k += 1024) {
    unsigned long long e = stage[k];
    unsigned int key = (unsigned int)e;
    int bk = key >> 15;  // r>>3
    unsigned int rank = k - offx[bk];
    if (rank < SLOT)
      seg[((size_t)bk * P1_BLOCKS + b) * SLOT + rank] = e;
  }
}

__global__ __launch_bounds__(1024) void p2_accum(
    const unsigned int* __restrict__ cnt_arr,
    const unsigned long long* __restrict__ seg,
    unsigned short* __restrict__ wb) {
  __shared__ float img[8 * 4096];  // 128 KB f32 row-image for 8 rows
  __shared__ unsigned int lcnt[P1_BLOCKS];
  const int b = blockIdx.x;  // bucket
  const int tid = threadIdx.x;
  floatx4* img4 = (floatx4*)img;
  for (int i = tid; i < 8192; i += 1024) img4[i] = (floatx4)0.0f;
  if (tid < P1_BLOCKS) {
    unsigned int c = cnt_arr[(size_t)b * P1_BLOCKS + tid];
    lcnt[tid] = c > SLOT ? SLOT : c;
  }
  __syncthreads();
  const unsigned long long* sbase = seg + (size_t)b * P1_BLOCKS * SLOT;
  for (int s = tid; s < P1_BLOCKS * SLOT; s += 1024) {
    int j = s / SLOT;
    int i = s - j * SLOT;
    if ((unsigned int)i < lcnt[j]) {
      unsigned long long e = sbase[s];
      unsigned int key = (unsigned int)e;
      union { unsigned int u; float f; } v;
      v.u = (unsigned int)(e >> 32);
      atomicAdd(&img[key & 0x7FFF], v.f);
    }
  }
  __syncthreads();
  unsigned short* dst = wb + (size_t)b * 8 * 4096;
  for (int i = tid; i < 4096; i += 1024) {
    floatx4 a = img4[i * 2];
    floatx4 f = img4[i * 2 + 1];
    ushort8 o;
    o[0] = f2bf(a[0]); o[1] = f2bf(a[1]); o[2] = f2bf(a[2]); o[3] = f2bf(a[3]);
    o[4] = f2bf(f[0]); o[5] = f2bf(f[1]); o[6] = f2bf(f[2]); o[7] = f2bf(f[3]);
    *(ushort8*)(dst + i * 8) = o;
  }
}

// ---------------------------------------------------------------------------
// bf16 MFMA GEMM, C = A * B^T + bias — 256x256 tile, BK=64, 8 waves (2Mx4N),
// 4 phases/K-tile, double-buffered LDS, counted vmcnt (T3+T4), setprio (T5),
// XOR-swizzled LDS (T2), XCD swizzle (T1).
// LOCKED at the R3 schedule (125-131us, MfmaUtil ~45%, ~1090 TF). R4's bf
// double-buffer regressed; R7's launch_bounds relaxation was neutral.
// Do not modify without a new counter-backed theory.
// ---------------------------------------------------------------------------
#define NT_K 64  // 4096 / BK=64

__device__ inline void load_lds16(const unsigned short* g,
                                  const unsigned short* lds_base) {
  __builtin_amdgcn_global_load_lds(
      (const __attribute__((address_space(1))) unsigned int*)g,
      (__attribute__((address_space(3))) unsigned int*)lds_base, 16, 0, 0);
}

#define SA(DST, tt, q)                                              \
  load_lds16(gA + (size_t)(q) * (64 * IN_F) + (size_t)(tt) * 64,    \
             lAst + (DST) + (q) * 4096)
#define SB(DST, tt, q)                                              \
  load_lds16(gB + (size_t)(q) * (64 * IN_F) + (size_t)(tt) * 64,    \
             lBst + (DST) + (q) * 4096)

#define PH_BAR()                                              \
  do {                                                        \
    asm volatile("" ::: "memory");                            \
    __builtin_amdgcn_s_barrier();                             \
    asm volatile("" ::: "memory");                            \
  } while (0)

#define VMW(n) asm volatile("s_waitcnt vmcnt(" #n ")" ::: "memory")

#define DSR(arr, idx) (*(const short8*)&(arr)[idx])

#define MFMA16(AF, M0, M1)                                                     \
  _Pragma("unroll") for (int j = 0; j < 4; ++j) {                              \
    acc[M0][j] = __builtin_amdgcn_mfma_f32_16x16x32_bf16(AF[0], bf[j][0],      \
                                                         acc[M0][j], 0, 0, 0); \
    acc[M0][j] = __builtin_amdgcn_mfma_f32_16x16x32_bf16(AF[1], bf[j][1],      \
                                                         acc[M0][j], 0, 0, 0); \
    acc[M1][j] = __builtin_amdgcn_mfma_f32_16x16x32_bf16(AF[2], bf[j][0],      \
                                                         acc[M1][j], 0, 0, 0); \
    acc[M1][j] = __builtin_amdgcn_mfma_f32_16x16x32_bf16(AF[3], bf[j][1],      \
                                                         acc[M1][j], 0, 0, 0); \
  }

// One K-tile, 4 phases. T runtime; BUF/NBUF compile-time (0 / 16384).
// DO_S1: stage A(T+1)q1/q3 | DO_S2: stage T+2 ops | DO_VM4/DO_VM0: vmcnt at
// ph2 | DO_RA: ph3 read-ahead (af next-tile + bf late).
#define TILE(T, BUF, NBUF, DO_S1, DO_S2, DO_VM4, DO_VM0, DO_RA)               \
  do {                                                                        \
    /* ---- ph0: MFMA M0,1 (afA) · read M2,3->afB · stage A(T+1)q1/q3 */      \
    afB[0] = DSR(lA, (BUF) + aqLo + (32 + rr) * 64 + kc0);                    \
    afB[1] = DSR(lA, (BUF) + aqLo + (32 + rr) * 64 + kc1);                    \
    afB[2] = DSR(lA, (BUF) + aqLo + (48 + rr) * 64 + kc0);                    \
    afB[3] = DSR(lA, (BUF) + aqLo + (48 + rr) * 64 + kc1);                    \
    if (DO_S1) { SA(NBUF, (T) + 1, 1); SA(NBUF, (T) + 1, 3); }                \
    PH_BAR();                                                                 \
    __builtin_amdgcn_s_setprio(1);                                            \
    MFMA16(afA, 0, 1);                                                        \
    __builtin_amdgcn_s_setprio(0);                                            \
    PH_BAR();                                                                 \
    /* ---- ph1: MFMA M2,3 (afB) · read M4,5->afA · stage B(T+2)q0/q1 */      \
    afA[0] = DSR(lA, (BUF) + aqHi + rr * 64 + kc0);                           \
    afA[1] = DSR(lA, (BUF) + aqHi + rr * 64 + kc1);                           \
    afA[2] = DSR(lA, (BUF) + aqHi + (16 + rr) * 64 + kc0);                    \
    afA[3] = DSR(lA, (BUF) + aqHi + (16 + rr) * 64 + kc1);                    \
    if (DO_S2) { SB(BUF, (T) + 2, 0); SB(BUF, (T) + 2, 1); }                  \
    PH_BAR();                                                                 \
    __builtin_amdgcn_s_setprio(1);                                            \
    MFMA16(afB, 2, 3);                                                        \
    __builtin_amdgcn_s_setprio(0);                                            \
    PH_BAR();                                                                 \
    /* ---- ph2: MFMA M4,5 (afA) · read M6,7->afB · stage B(T+2)q2/q3 ·       \
            vmcnt => tile T+1 confirmed */                                    \
    afB[0] = DSR(lA, (BUF) + aqHi + (32 + rr) * 64 + kc0);                    \
    afB[1] = DSR(lA, (BUF) + aqHi + (32 + rr) * 64 + kc1);                    \
    afB[2] = DSR(lA, (BUF) + aqHi + (48 + rr) * 64 + kc0);                    \
    afB[3] = DSR(lA, (BUF) + aqHi + (48 + rr) * 64 + kc1);                    \
    if (DO_S2) { SB(BUF, (T) + 2, 2); SB(BUF, (T) + 2, 3); }                  \
    PH_BAR();                                                                 \
    __builtin_amdgcn_s_setprio(1);                                            \
    MFMA16(afA, 4, 5);                                                        \
    __builtin_amdgcn_s_setprio(0);                                            \
    if (DO_VM4) VMW(4);                                                       \
    if (DO_VM0) VMW(0);                                                       \
    PH_BAR();                                                                 \
    /* ---- ph3: MFMA M6,7 (afB) · read T+1 M0,1->afA · stage A(T+2)q0/q2 ·   \
            late-read bf(T+1) after MFMA (WAR, drains under pipe) */          \
    if (DO_RA) {                                                              \
      afA[0] = DSR(lA, (NBUF) + aqLo + rr * 64 + kc0);                        \
      afA[1] = DSR(lA, (NBUF) + aqLo + rr * 64 + kc1);                        \
      afA[2] = DSR(lA, (NBUF) + aqLo + (16 + rr) * 64 + kc0);                 \
      afA[3] = DSR(lA, (NBUF) + aqLo + (16 + rr) * 64 + kc1);                 \
    }                                                                         \
    if (DO_S2) { SA(BUF, (T) + 2, 0); SA(BUF, (T) + 2, 2); }                  \
    PH_BAR();                                                                 \
    __builtin_amdgcn_s_setprio(1);                                            \
    MFMA16(afB, 6, 7);                                                        \
    __builtin_amdgcn_s_setprio(0);                                            \
    if (DO_RA) {                                                              \
      _Pragma("unroll") for (int j = 0; j < 4; ++j) {                         \
        bf[j][0] = DSR(lB, (NBUF) + bq + (j * 16 + rr) * 64 + kc0);           \
        bf[j][1] = DSR(lB, (NBUF) + bq + (j * 16 + rr) * 64 + kc1);           \
      }                                                                       \
    }                                                                         \
    PH_BAR();                                                                 \
  } while (0)

__global__ __launch_bounds__(512) void gemm_bt_bf16(
    const unsigned short* __restrict__ A, const unsigned short* __restrict__ Bt,
    const float* __restrict__ bias, float* __restrict__ C) {
  __shared__ unsigned short lA[2 * 16384];  // 64 KB: 2 bufs x [4][64][64]
  __shared__ unsigned short lB[2 * 16384];  // 64 KB

  const int tid = threadIdx.x;
  const int wid = tid >> 6;
  const int lane = tid & 63;
  const int wm = (wid >> 2) * 128;  // warp_m * 128
  const int wn = (wid & 3) * 64;    // warp_n * 64

  // bijective XCD-aware swizzle, nwg = 256 (divisible by 8)
  int lin = blockIdx.y * 16 + blockIdx.x;
  lin = (lin & 7) * 32 + (lin >> 3);
  const int bm0 = (lin >> 4) * 256;
  const int bn0 = (lin & 15) * 256;

  // staging: one call = 64 rows x 64 cols (8 KB); thread -> (row, chunk).
  // Global source pre-swizzled so linear LDS holds chunk c = gchunk^(row&7).
  const int srow = tid >> 3;                      // 0..63
  const int scol = ((tid & 7) ^ (srow & 7)) * 8;  // swizzled col chunk
  const unsigned short* gA = A + (size_t)(bm0 + srow) * IN_F + scol;
  const unsigned short* gB = Bt + (size_t)(bn0 + srow) * IN_F + scol;
  unsigned short* lAst = lA + wid * 512;  // wave-uniform dest base
  unsigned short* lBst = lB + wid * 512;

  // fragment-read indices
  const int rr = lane & 15;
  const int kq = lane >> 4;       // k-chunk within MFMA K=32
  const int rx = rr & 7;
  const int kc0 = (kq ^ rx) * 8;  // swizzled chunk, ks=0
  const int kc1 = kc0 ^ 32;       // ks=1 (chunk ^ 4)
  const int aqLo = (wm >> 6) * 4096;  // warp_m's first A-quarter
  const int aqHi = aqLo + 4096;
  const int bq = (wn >> 6) * 4096;    // warp_n's B-quarter

  floatx4 acc[8][4];
#pragma unroll
  for (int i = 0; i < 8; ++i)
#pragma unroll
    for (int j = 0; j < 4; ++j) acc[i][j] = (floatx4)0.0f;

  short8 bf[4][2];
  short8 afA[4], afB[4];

  // ---- prologue: A(0) B(0) B(1) fully + A(1)q0/q2 (14 loads) ----
#pragma unroll
  for (int q = 0; q < 4; ++q) SA(0, 0, q);
#pragma unroll
  for (int q = 0; q < 4; ++q) SB(0, 0, q);
#pragma unroll
  for (int q = 0; q < 4; ++q) SB(16384, 1, q);
  SA(16384, 1, 0);
  SA(16384, 1, 2);
  VMW(6);  // confirm tile 0; keep B(1)x4 + A(1)q0/q2 in flight
  PH_BAR();
  // preload regs for tile 0 ph0: bf = B(0), afA = A(0) M0,1
#pragma unroll
  for (int j = 0; j < 4; ++j) {
    bf[j][0] = DSR(lB, bq + (j * 16 + rr) * 64 + kc0);
    bf[j][1] = DSR(lB, bq + (j * 16 + rr) * 64 + kc1);
  }
  afA[0] = DSR(lA, aqLo + rr * 64 + kc0);
  afA[1] = DSR(lA, aqLo + rr * 64 + kc1);
  afA[2] = DSR(lA, aqLo + (16 + rr) * 64 + kc0);
  afA[3] = DSR(lA, aqLo + (16 + rr) * 64 + kc1);

  // ---- main loop: branch-free steady state, tiles 0..61 ----
  for (int t = 0; t < NT_K - 2; t += 2) {
    TILE(t, 0, 16384, 1, 1, 1, 0, 1);
    TILE(t + 1, 16384, 0, 1, 1, 1, 0, 1);
  }
  // ---- peeled tail ----
  TILE(NT_K - 2, 0, 16384, 1, 0, 0, 1, 1);  // t=62: stage A(63)q1/q3, drain
  TILE(NT_K - 1, 16384, 0, 0, 0, 0, 0, 0);  // t=63: pure compute

  // ---- epilogue: C = acc + bias ----
  const int cn = lane & 15;
  const int r0 = (lane >> 4) * 4;
#pragma unroll
  for (int j = 0; j < 4; ++j) {
    const int col = bn0 + wn + j * 16 + cn;
    const float bv = bias[col];
#pragma unroll
    for (int i = 0; i < 8; ++i) {
#pragma unroll
      for (int r = 0; r < 4; ++r) {
        const int row = bm0 + wm + i * 16 + r0 + r;
        C[(size_t)row * OUT_F + col] = acc[i][j][r] + bv;
      }
    }
  }
}

// ---------------------------------------------------------------------------
extern "C" void kernel_launch(void* const* d_in, const int* in_sizes, int n_in,
                              void* d_out, int out_size, void* d_ws,
                              size_t ws_size, hipStream_t stream) {
  const float* x = (const float*)d_in[0];
  const float* vals = (const float*)d_in[1];
  const int* rows = (const int*)d_in[2];
  const int* cols = (const int*)d_in[3];
  const float* bias = (const float*)d_in[4];
  float* out = (float*)d_out;

  // ws layout: cnt_arr 206KB @0 | seg 30.6MB @1MB | wb 32MB @32MB |
  //            xb 32MB @64MB   (no memset needed: cnt_arr is plain-stored)
  unsigned int* cnt_arr = (unsigned int*)d_ws;
  unsigned long long* seg =
      (unsigned long long*)((char*)d_ws + ((size_t)1 << 20));
  unsigned short* wb = (unsigned short*)((char*)d_ws + ((size_t)32 << 20));
  unsigned short* xb = (unsigned short*)((char*)d_ws + ((size_t)64 << 20));

  p1_bucket<<<P1_BLOCKS, 1024, 0, stream>>>(vals, rows, cols, cnt_arr, seg);
  cvt_x<<<CVT_BLOCKS, CVT_THREADS, 0, stream>>>(x, xb);
  p2_accum<<<NBUCK, 1024, 0, stream>>>(cnt_arr, seg, wb);

  gemm_bt_bf16<<<dim3(16, 16), 512, 0, stream>>>(xb, wb, bias, out);
}

// Round 12
// 275.646 us; speedup vs baseline: 1.0932x; 1.0932x over previous
//
#include <hip/hip_runtime.h>
#include <hip/hip_bf16.h>
#include <cstdint>
#include <cstddef>

#define B_DIM 4096
#define IN_F 4096
#define OUT_F 4096
#define NNZ_N 1677722

typedef short short8 __attribute__((ext_vector_type(8)));
typedef float floatx4 __attribute__((ext_vector_type(4)));
typedef unsigned short ushort8 __attribute__((ext_vector_type(8)));

// ---------------------------------------------------------------------------
// f32 -> bf16 RNE
// ---------------------------------------------------------------------------
__device__ inline unsigned short f2bf(float f) {
  union { float f; unsigned int u; } v;
  v.f = f;
  unsigned int u = v.u;
  return (unsigned short)((u + 0x7fffu + ((u >> 16) & 1u)) >> 16);
}

// ---------------------------------------------------------------------------
// Bucketed densification, R12 = R11 resubmitted (R11 was an infra flake —
// same signature as R2/R5, both of which passed on identical resubmit).
// Best-measured R8 structure:
//   - cvt FUSED into p1's grid (R10 proved splitting costs +21us: the
//     2048 cvt rider blocks overlap p1's low-occupancy bucket phase).
//   - P1_CHUNK=8192 -> stage 64KB + 10KB aux = 74KB LDS -> 2 blocks/CU
//     for the riders (R8's edge over R9's 128KB/1-per-CU variant).
//   - R8 data path: LDS-ordered stage + coalesced copy-out (wave's stores
//     span ~8 lines not 64), global-cursor reservation, contiguous
//     per-bucket seg runs for p2.
//   - Only R9 piece kept: 2-barrier wave-0 shuffle scan (replaces R8's
//     18-barrier Hillis-Steele; strictly fewer block-wide barriers).
// ---------------------------------------------------------------------------
#define P1_CHUNK 8192
#define P1_BLOCKS ((NNZ_N + P1_CHUNK - 1) / P1_CHUNK)  // 205
#define NBUCK 512                                      // 8 rows per bucket
#define CAP 5120                                       // expect ~3276 +- 57
#define CVT_BLOCKS ((B_DIM * IN_F) / 8 / 1024)         // 2048

__global__ __launch_bounds__(1024) void p1_bucket_cvt(
    const float* __restrict__ vals, const int* __restrict__ rows,
    const int* __restrict__ cols, unsigned int* __restrict__ gcursor,
    unsigned long long* __restrict__ seg, const float* __restrict__ x,
    unsigned short* __restrict__ xb) {
  __shared__ unsigned int cnt[NBUCK];    // per-bucket count
  __shared__ unsigned int off[NBUCK];    // inclusive scan
  __shared__ unsigned int offx[NBUCK];   // exclusive offsets
  __shared__ unsigned int cur2[NBUCK];   // placement cursors
  __shared__ unsigned int gbase[NBUCK];  // global reserved bases
  __shared__ unsigned long long stage[P1_CHUNK];  // 64 KB bucket-ordered
  const int b = blockIdx.x;
  const int tid = threadIdx.x;
  if (b < P1_BLOCKS) {
    if (tid < NBUCK) cnt[tid] = 0;
    __syncthreads();
    const int base = b * P1_CHUNK;
    // ---- pass A: histogram ----
#pragma unroll
    for (int j = 0; j < P1_CHUNK / 1024; ++j) {
      int idx = base + j * 1024 + tid;
      if (idx < NNZ_N) atomicAdd(&cnt[rows[idx] >> 3], 1u);
    }
    __syncthreads();
    // ---- scan: wave 0 scans all 512 buckets (serial-8 + shfl_up) ----
    if (tid < 64) {
      unsigned int a[8];
#pragma unroll
      for (int i = 0; i < 8; ++i) a[i] = cnt[tid * 8 + i];
#pragma unroll
      for (int i = 1; i < 8; ++i) a[i] += a[i - 1];
      unsigned int ls = a[7];
      unsigned int sc = ls;
#pragma unroll
      for (int d = 1; d < 64; d <<= 1) {
        unsigned int o = __shfl_up(sc, d, 64);
        if (tid >= d) sc += o;
      }
      unsigned int excl = sc - ls;
#pragma unroll
      for (int i = 0; i < 8; ++i) off[tid * 8 + i] = a[i] + excl;
    }
    __syncthreads();
    if (tid < NBUCK) {
      unsigned int e = off[tid] - cnt[tid];
      offx[tid] = e;
      cur2[tid] = e;
      gbase[tid] = atomicAdd(&gcursor[tid], cnt[tid]);
    }
    __syncthreads();
    // ---- pass B: ranked placement into LDS stage (bucket-ordered) ----
#pragma unroll
    for (int j = 0; j < P1_CHUNK / 1024; ++j) {
      int idx = base + j * 1024 + tid;
      if (idx < NNZ_N) {
        int r = rows[idx];
        int c = cols[idx];
        union { float f; unsigned int u; } v;
        v.f = vals[idx];
        unsigned int slot = atomicAdd(&cur2[r >> 3], 1u);
        unsigned int key = (((unsigned int)r) << 12) | (unsigned int)c;
        stage[slot] = ((unsigned long long)v.u << 32) | key;
      }
    }
    __syncthreads();
    // ---- pass C: coalesced copy-out (consecutive threads -> consecutive
    //      slots -> contiguous runs per bucket) ----
    unsigned int tot = off[NBUCK - 1];
    for (unsigned int k = tid; k < tot; k += 1024) {
      unsigned long long e = stage[k];
      unsigned int key = (unsigned int)e;
      int bk = key >> 15;  // r>>3
      unsigned int pos = gbase[bk] + (k - offx[bk]);
      if (pos < CAP) seg[(size_t)bk * CAP + pos] = e;
    }
  } else {
    size_t i = ((size_t)(b - P1_BLOCKS) * 1024 + tid) * 8;
    float4 a = *(const float4*)(x + i);
    float4 f = *(const float4*)(x + i + 4);
    ushort8 o;
    o[0] = f2bf(a.x); o[1] = f2bf(a.y); o[2] = f2bf(a.z); o[3] = f2bf(a.w);
    o[4] = f2bf(f.x); o[5] = f2bf(f.y); o[6] = f2bf(f.z); o[7] = f2bf(f.w);
    *(ushort8*)(xb + i) = o;
  }
}

__global__ __launch_bounds__(1024) void p2_accum(
    const unsigned int* __restrict__ gcursor,
    const unsigned long long* __restrict__ seg,
    unsigned short* __restrict__ wb) {
  __shared__ float img[8 * 4096];  // 128 KB f32 row-image for 8 rows
  const int b = blockIdx.x;
  const int tid = threadIdx.x;
  floatx4* img4 = (floatx4*)img;
  for (int i = tid; i < 8192; i += 1024) img4[i] = (floatx4)0.0f;
  __syncthreads();
  unsigned int n = gcursor[b];
  if (n > CAP) n = CAP;
  const unsigned long long* s = seg + (size_t)b * CAP;
  for (unsigned int i = tid; i < n; i += 1024) {
    unsigned long long e = s[i];
    unsigned int key = (unsigned int)e;
    union { unsigned int u; float f; } v;
    v.u = (unsigned int)(e >> 32);
    atomicAdd(&img[key & 0x7FFF], v.f);
  }
  __syncthreads();
  unsigned short* dst = wb + (size_t)b * 8 * 4096;
  for (int i = tid; i < 4096; i += 1024) {
    floatx4 a = img4[i * 2];
    floatx4 f = img4[i * 2 + 1];
    ushort8 o;
    o[0] = f2bf(a[0]); o[1] = f2bf(a[1]); o[2] = f2bf(a[2]); o[3] = f2bf(a[3]);
    o[4] = f2bf(f[0]); o[5] = f2bf(f[1]); o[6] = f2bf(f[2]); o[7] = f2bf(f[3]);
    *(ushort8*)(dst + i * 8) = o;
  }
}

// ---------------------------------------------------------------------------
// bf16 MFMA GEMM, C = A * B^T + bias — 256x256 tile, BK=64, 8 waves (2Mx4N),
// 4 phases/K-tile, double-buffered LDS, counted vmcnt (T3+T4), setprio (T5),
// XOR-swizzled LDS (T2), XCD swizzle (T1).
// LOCKED at the R3 schedule (125-131us, MfmaUtil ~45%, ~1090 TF). R4's bf
// double-buffer regressed; R7's launch_bounds relaxation was neutral.
// Do not modify without a new counter-backed theory.
// ---------------------------------------------------------------------------
#define NT_K 64  // 4096 / BK=64

__device__ inline void load_lds16(const unsigned short* g,
                                  const unsigned short* lds_base) {
  __builtin_amdgcn_global_load_lds(
      (const __attribute__((address_space(1))) unsigned int*)g,
      (__attribute__((address_space(3))) unsigned int*)lds_base, 16, 0, 0);
}

#define SA(DST, tt, q)                                              \
  load_lds16(gA + (size_t)(q) * (64 * IN_F) + (size_t)(tt) * 64,    \
             lAst + (DST) + (q) * 4096)
#define SB(DST, tt, q)                                              \
  load_lds16(gB + (size_t)(q) * (64 * IN_F) + (size_t)(tt) * 64,    \
             lBst + (DST) + (q) * 4096)

#define PH_BAR()                                              \
  do {                                                        \
    asm volatile("" ::: "memory");                            \
    __builtin_amdgcn_s_barrier();                             \
    asm volatile("" ::: "memory");                            \
  } while (0)

#define VMW(n) asm volatile("s_waitcnt vmcnt(" #n ")" ::: "memory")

#define DSR(arr, idx) (*(const short8*)&(arr)[idx])

#define MFMA16(AF, M0, M1)                                                     \
  _Pragma("unroll") for (int j = 0; j < 4; ++j) {                              \
    acc[M0][j] = __builtin_amdgcn_mfma_f32_16x16x32_bf16(AF[0], bf[j][0],      \
                                                         acc[M0][j], 0, 0, 0); \
    acc[M0][j] = __builtin_amdgcn_mfma_f32_16x16x32_bf16(AF[1], bf[j][1],      \
                                                         acc[M0][j], 0, 0, 0); \
    acc[M1][j] = __builtin_amdgcn_mfma_f32_16x16x32_bf16(AF[2], bf[j][0],      \
                                                         acc[M1][j], 0, 0, 0); \
    acc[M1][j] = __builtin_amdgcn_mfma_f32_16x16x32_bf16(AF[3], bf[j][1],      \
                                                         acc[M1][j], 0, 0, 0); \
  }

// One K-tile, 4 phases. T runtime; BUF/NBUF compile-time (0 / 16384).
// DO_S1: stage A(T+1)q1/q3 | DO_S2: stage T+2 ops | DO_VM4/DO_VM0: vmcnt at
// ph2 | DO_RA: ph3 read-ahead (af next-tile + bf late).
#define TILE(T, BUF, NBUF, DO_S1, DO_S2, DO_VM4, DO_VM0, DO_RA)               \
  do {                                                                        \
    /* ---- ph0: MFMA M0,1 (afA) · read M2,3->afB · stage A(T+1)q1/q3 */      \
    afB[0] = DSR(lA, (BUF) + aqLo + (32 + rr) * 64 + kc0);                    \
    afB[1] = DSR(lA, (BUF) + aqLo + (32 + rr) * 64 + kc1);                    \
    afB[2] = DSR(lA, (BUF) + aqLo + (48 + rr) * 64 + kc0);                    \
    afB[3] = DSR(lA, (BUF) + aqLo + (48 + rr) * 64 + kc1);                    \
    if (DO_S1) { SA(NBUF, (T) + 1, 1); SA(NBUF, (T) + 1, 3); }                \
    PH_BAR();                                                                 \
    __builtin_amdgcn_s_setprio(1);                                            \
    MFMA16(afA, 0, 1);                                                        \
    __builtin_amdgcn_s_setprio(0);                                            \
    PH_BAR();                                                                 \
    /* ---- ph1: MFMA M2,3 (afB) · read M4,5->afA · stage B(T+2)q0/q1 */      \
    afA[0] = DSR(lA, (BUF) + aqHi + rr * 64 + kc0);                           \
    afA[1] = DSR(lA, (BUF) + aqHi + rr * 64 + kc1);                           \
    afA[2] = DSR(lA, (BUF) + aqHi + (16 + rr) * 64 + kc0);                    \
    afA[3] = DSR(lA, (BUF) + aqHi + (16 + rr) * 64 + kc1);                    \
    if (DO_S2) { SB(BUF, (T) + 2, 0); SB(BUF, (T) + 2, 1); }                  \
    PH_BAR();                                                                 \
    __builtin_amdgcn_s_setprio(1);                                            \
    MFMA16(afB, 2, 3);                                                        \
    __builtin_amdgcn_s_setprio(0);                                            \
    PH_BAR();                                                                 \
    /* ---- ph2: MFMA M4,5 (afA) · read M6,7->afB · stage B(T+2)q2/q3 ·       \
            vmcnt => tile T+1 confirmed */                                    \
    afB[0] = DSR(lA, (BUF) + aqHi + (32 + rr) * 64 + kc0);                    \
    afB[1] = DSR(lA, (BUF) + aqHi + (32 + rr) * 64 + kc1);                    \
    afB[2] = DSR(lA, (BUF) + aqHi + (48 + rr) * 64 + kc0);                    \
    afB[3] = DSR(lA, (BUF) + aqHi + (48 + rr) * 64 + kc1);                    \
    if (DO_S2) { SB(BUF, (T) + 2, 2); SB(BUF, (T) + 2, 3); }                  \
    PH_BAR();                                                                 \
    __builtin_amdgcn_s_setprio(1);                                            \
    MFMA16(afA, 4, 5);                                                        \
    __builtin_amdgcn_s_setprio(0);                                            \
    if (DO_VM4) VMW(4);                                                       \
    if (DO_VM0) VMW(0);                                                       \
    PH_BAR();                                                                 \
    /* ---- ph3: MFMA M6,7 (afB) · read T+1 M0,1->afA · stage A(T+2)q0/q2 ·   \
            late-read bf(T+1) after MFMA (WAR, drains under pipe) */          \
    if (DO_RA) {                                                              \
      afA[0] = DSR(lA, (NBUF) + aqLo + rr * 64 + kc0);                        \
      afA[1] = DSR(lA, (NBUF) + aqLo + rr * 64 + kc1);                        \
      afA[2] = DSR(lA, (NBUF) + aqLo + (16 + rr) * 64 + kc0);                 \
      afA[3] = DSR(lA, (NBUF) + aqLo + (16 + rr) * 64 + kc1);                 \
    }                                                                         \
    if (DO_S2) { SA(BUF, (T) + 2, 0); SA(BUF, (T) + 2, 2); }                  \
    PH_BAR();                                                                 \
    __builtin_amdgcn_s_setprio(1);                                            \
    MFMA16(afB, 6, 7);                                                        \
    __builtin_amdgcn_s_setprio(0);                                            \
    if (DO_RA) {                                                              \
      _Pragma("unroll") for (int j = 0; j < 4; ++j) {                         \
        bf[j][0] = DSR(lB, (NBUF) + bq + (j * 16 + rr) * 64 + kc0);           \
        bf[j][1] = DSR(lB, (NBUF) + bq + (j * 16 + rr) * 64 + kc1);           \
      }                                                                       \
    }                                                                         \
    PH_BAR();                                                                 \
  } while (0)

__global__ __launch_bounds__(512) void gemm_bt_bf16(
    const unsigned short* __restrict__ A, const unsigned short* __restrict__ Bt,
    const float* __restrict__ bias, float* __restrict__ C) {
  __shared__ unsigned short lA[2 * 16384];  // 64 KB: 2 bufs x [4][64][64]
  __shared__ unsigned short lB[2 * 16384];  // 64 KB

  const int tid = threadIdx.x;
  const int wid = tid >> 6;
  const int lane = tid & 63;
  const int wm = (wid >> 2) * 128;  // warp_m * 128
  const int wn = (wid & 3) * 64;    // warp_n * 64

  // bijective XCD-aware swizzle, nwg = 256 (divisible by 8)
  int lin = blockIdx.y * 16 + blockIdx.x;
  lin = (lin & 7) * 32 + (lin >> 3);
  const int bm0 = (lin >> 4) * 256;
  const int bn0 = (lin & 15) * 256;

  // staging: one call = 64 rows x 64 cols (8 KB); thread -> (row, chunk).
  // Global source pre-swizzled so linear LDS holds chunk c = gchunk^(row&7).
  const int srow = tid >> 3;                      // 0..63
  const int scol = ((tid & 7) ^ (srow & 7)) * 8;  // swizzled col chunk
  const unsigned short* gA = A + (size_t)(bm0 + srow) * IN_F + scol;
  const unsigned short* gB = Bt + (size_t)(bn0 + srow) * IN_F + scol;
  unsigned short* lAst = lA + wid * 512;  // wave-uniform dest base
  unsigned short* lBst = lB + wid * 512;

  // fragment-read indices
  const int rr = lane & 15;
  const int kq = lane >> 4;       // k-chunk within MFMA K=32
  const int rx = rr & 7;
  const int kc0 = (kq ^ rx) * 8;  // swizzled chunk, ks=0
  const int kc1 = kc0 ^ 32;       // ks=1 (chunk ^ 4)
  const int aqLo = (wm >> 6) * 4096;  // warp_m's first A-quarter
  const int aqHi = aqLo + 4096;
  const int bq = (wn >> 6) * 4096;    // warp_n's B-quarter

  floatx4 acc[8][4];
#pragma unroll
  for (int i = 0; i < 8; ++i)
#pragma unroll
    for (int j = 0; j < 4; ++j) acc[i][j] = (floatx4)0.0f;

  short8 bf[4][2];
  short8 afA[4], afB[4];

  // ---- prologue: A(0) B(0) B(1) fully + A(1)q0/q2 (14 loads) ----
#pragma unroll
  for (int q = 0; q < 4; ++q) SA(0, 0, q);
#pragma unroll
  for (int q = 0; q < 4; ++q) SB(0, 0, q);
#pragma unroll
  for (int q = 0; q < 4; ++q) SB(16384, 1, q);
  SA(16384, 1, 0);
  SA(16384, 1, 2);
  VMW(6);  // confirm tile 0; keep B(1)x4 + A(1)q0/q2 in flight
  PH_BAR();
  // preload regs for tile 0 ph0: bf = B(0), afA = A(0) M0,1
#pragma unroll
  for (int j = 0; j < 4; ++j) {
    bf[j][0] = DSR(lB, bq + (j * 16 + rr) * 64 + kc0);
    bf[j][1] = DSR(lB, bq + (j * 16 + rr) * 64 + kc1);
  }
  afA[0] = DSR(lA, aqLo + rr * 64 + kc0);
  afA[1] = DSR(lA, aqLo + rr * 64 + kc1);
  afA[2] = DSR(lA, aqLo + (16 + rr) * 64 + kc0);
  afA[3] = DSR(lA, aqLo + (16 + rr) * 64 + kc1);

  // ---- main loop: branch-free steady state, tiles 0..61 ----
  for (int t = 0; t < NT_K - 2; t += 2) {
    TILE(t, 0, 16384, 1, 1, 1, 0, 1);
    TILE(t + 1, 16384, 0, 1, 1, 1, 0, 1);
  }
  // ---- peeled tail ----
  TILE(NT_K - 2, 0, 16384, 1, 0, 0, 1, 1);  // t=62: stage A(63)q1/q3, drain
  TILE(NT_K - 1, 16384, 0, 0, 0, 0, 0, 0);  // t=63: pure compute

  // ---- epilogue: C = acc + bias ----
  const int cn = lane & 15;
  const int r0 = (lane >> 4) * 4;
#pragma unroll
  for (int j = 0; j < 4; ++j) {
    const int col = bn0 + wn + j * 16 + cn;
    const float bv = bias[col];
#pragma unroll
    for (int i = 0; i < 8; ++i) {
#pragma unroll
      for (int r = 0; r < 4; ++r) {
        const int row = bm0 + wm + i * 16 + r0 + r;
        C[(size_t)row * OUT_F + col] = acc[i][j][r] + bv;
      }
    }
  }
}

// ---------------------------------------------------------------------------
extern "C" void kernel_launch(void* const* d_in, const int* in_sizes, int n_in,
                              void* d_out, int out_size, void* d_ws,
                              size_t ws_size, hipStream_t stream) {
  const float* x = (const float*)d_in[0];
  const float* vals = (const float*)d_in[1];
  const int* rows = (const int*)d_in[2];
  const int* cols = (const int*)d_in[3];
  const float* bias = (const float*)d_in[4];
  float* out = (float*)d_out;

  // ws layout: gcursor 2KB @0 | seg 20MB @1MB | wb 32MB @32MB | xb 32MB @64MB
  unsigned int* gcursor = (unsigned int*)d_ws;
  unsigned long long* seg =
      (unsigned long long*)((char*)d_ws + ((size_t)1 << 20));
  unsigned short* wb = (unsigned short*)((char*)d_ws + ((size_t)32 << 20));
  unsigned short* xb = (unsigned short*)((char*)d_ws + ((size_t)64 << 20));

  (void)hipMemsetAsync(gcursor, 0, NBUCK * sizeof(unsigned int), stream);
  p1_bucket_cvt<<<P1_BLOCKS + CVT_BLOCKS, 1024, 0, stream>>>(
      vals, rows, cols, gcursor, seg, x, xb);
  p2_accum<<<NBUCK, 1024, 0, stream>>>(gcursor, seg, wb);

  gemm_bt_bf16<<<dim3(16, 16), 512, 0, stream>>>(xb, wb, bias, out);
}